// Round 2
// baseline (345.476 us; speedup 1.0000x reference)
//
#include <hip/hip_runtime.h>
#include <stdint.h>

#define DM   1024
#define DQ   64
#define NB   4
#define TT   4096
#define MTOT (NB*TT)

#define QB   64
#define KB   64
#define DVS  256
#define C_EXP 0.18033688011112042f   // log2(e)/8  (folds the 1/sqrt(64) scale)

typedef __attribute__((ext_vector_type(8))) short short8;
typedef __attribute__((ext_vector_type(4))) float f32x4;

__device__ __forceinline__ unsigned short f2bf(float f) {
  union { float f; uint32_t u; } v; v.f = f;
  return (unsigned short)((v.u + 0x7FFFu + ((v.u >> 16) & 1u)) >> 16);
}

// ---------------- converts / packs ----------------
__global__ void k_cvt_x(const float* __restrict__ X, unsigned short* __restrict__ Xb) {
  int i = (blockIdx.x * 256 + threadIdx.x) * 4;
  float4 v = *(const float4*)(X + i);
  unsigned short o[4] = {f2bf(v.x), f2bf(v.y), f2bf(v.z), f2bf(v.w)};
  *(uint2*)(Xb + i) = *(uint2*)o;
}

// WqkT[n][k], n in [0,128): cols 0..63 = Wq, 64..127 = Wk (stored K-contiguous = B^T)
__global__ void k_pack_wqk(const float* __restrict__ Wq, const float* __restrict__ Wk,
                           unsigned short* __restrict__ WqkT) {
  int k = blockIdx.x * 256 + threadIdx.x;
  int n = blockIdx.y;
  float v = (n < DQ) ? Wq[(size_t)k * DQ + n] : Wk[(size_t)k * DQ + (n - DQ)];
  WqkT[(size_t)n * DM + k] = f2bf(v);
}

__global__ void k_pack_wv(const float* __restrict__ Wv, unsigned short* __restrict__ WvT) {
  int k = blockIdx.x * 256 + threadIdx.x;
  int n = blockIdx.y;
  WvT[(size_t)n * DM + k] = f2bf(Wv[(size_t)k * DM + n]);
}

// ---------------- GEMM: C[M,N] = A[M,K] * Bt[N,K]^T  (m97 structure) ----------------
// TSTORE=false: C row-major bf16 [M][N].  TSTORE=true: C = Vt[b][n][t] (t = m%4096).
template<bool TSTORE>
__global__ __launch_bounds__(256, 2) void k_gemm(
    const unsigned short* __restrict__ A, const unsigned short* __restrict__ Bt,
    unsigned short* __restrict__ C, int M, int N, int K) {
  __shared__ unsigned short As[128 * 32];
  __shared__ unsigned short Bs[128 * 32];
  int tid = threadIdx.x;
  int lane = tid & 63;
  int w = tid >> 6;
  int lo = lane & 15, hi = lane >> 4;
  int bm = blockIdx.x * 128, bn = blockIdx.y * 128;
  int wr = (w >> 1) * 64, wc = (w & 1) * 64;
  f32x4 acc[4][4] = {};
  int arow = tid >> 2, koff = (tid & 3) * 8;
  const unsigned short* Ag = A  + (size_t)(bm + arow) * K + koff;
  const unsigned short* Bg = Bt + (size_t)(bn + arow) * K + koff;

  for (int kt = 0; kt < K; kt += 32) {
    __builtin_amdgcn_global_load_lds((const __attribute__((address_space(1))) void*)(Ag + kt),
        (__attribute__((address_space(3))) void*)(As + tid * 8), 16, 0, 0);
    __builtin_amdgcn_global_load_lds((const __attribute__((address_space(1))) void*)(Ag + (size_t)64 * K + kt),
        (__attribute__((address_space(3))) void*)(As + 2048 + tid * 8), 16, 0, 0);
    __builtin_amdgcn_global_load_lds((const __attribute__((address_space(1))) void*)(Bg + kt),
        (__attribute__((address_space(3))) void*)(Bs + tid * 8), 16, 0, 0);
    __builtin_amdgcn_global_load_lds((const __attribute__((address_space(1))) void*)(Bg + (size_t)64 * K + kt),
        (__attribute__((address_space(3))) void*)(Bs + 2048 + tid * 8), 16, 0, 0);
    __syncthreads();
    short8 af[4], bfr[4];
#pragma unroll
    for (int i = 0; i < 4; i++)
      af[i] = *(const short8*)(As + (wr + i * 16 + lo) * 32 + hi * 8);
#pragma unroll
    for (int j = 0; j < 4; j++)
      bfr[j] = *(const short8*)(Bs + (wc + j * 16 + lo) * 32 + hi * 8);
#pragma unroll
    for (int i = 0; i < 4; i++)
#pragma unroll
      for (int j = 0; j < 4; j++)
        acc[i][j] = __builtin_amdgcn_mfma_f32_16x16x32_bf16(af[i], bfr[j], acc[i][j], 0, 0, 0);
    __syncthreads();
  }

  if (!TSTORE) {
#pragma unroll
    for (int i = 0; i < 4; i++)
#pragma unroll
      for (int j = 0; j < 4; j++) {
        int r0 = bm + wr + i * 16 + hi * 4;
        int c0 = bn + wc + j * 16 + lo;
#pragma unroll
        for (int r = 0; r < 4; r++)
          C[(size_t)(r0 + r) * N + c0] = f2bf(acc[i][j][r]);
      }
  } else {
#pragma unroll
    for (int i = 0; i < 4; i++)
#pragma unroll
      for (int j = 0; j < 4; j++) {
        int m0 = bm + wr + i * 16 + hi * 4;
        int c0 = bn + wc + j * 16 + lo;
        int bb = m0 >> 12, t0 = m0 & (TT - 1);
        unsigned short o[4];
#pragma unroll
        for (int r = 0; r < 4; r++) o[r] = f2bf(acc[i][j][r]);
        *(uint2*)(C + ((size_t)bb * DM + c0) * TT + t0) = *(uint2*)o;
      }
  }
}

// ---------------- flash attention (causal), one dv-slice of 256 per block ----------------
// grid: 512 = 32 qt-pairs * 4 slices * 4 batches; 4 waves, wave owns 16 q-rows.
// Swapped S: S^T[key][q] = mfma(K_frag, Q^T_frag). Softmax per q fully lane-local + 2 shfl.
__global__ __launch_bounds__(256, 2) void k_flash(
    const unsigned short* __restrict__ QKb,  // [B*T][128]: cols 0-63 Q, 64-127 K (bf16)
    const unsigned short* __restrict__ Vt,   // [B][DM][T] bf16
    float* __restrict__ Out) {               // [B][T][DM] fp32
  __shared__ unsigned short Ks[KB * 64];     // [key][dq]  XOR-swizzled rows (8KB)
  __shared__ unsigned short Vs[DVS * KB];    // [dv][key]  XOR-swizzled rows (32KB)
  __shared__ unsigned short Ps[4][16 * KB];  // per-wave [q][key] XOR-swizzled (8KB)

  int tid = threadIdx.x, lane = tid & 63, w = tid >> 6;
  int lo = lane & 15, hi = lane >> 4;
  int bx = blockIdx.x;
  int slice = bx & 3;
  int tmp = bx >> 2;
  int pair = tmp & 31;
  int b = tmp >> 5;

  const char* kgb = (const char*)QKb + (size_t)b * TT * 256 + 128;
  const char* vgb = (const char*)Vt + ((size_t)b * DM + (size_t)slice * DVS) * (TT * 2);

  for (int half = 0; half < 2; half++) {
    int qt = half ? (63 - pair) : pair;    // (light, heavy) pair: constant work per block
    int qg0 = qt * QB + w * 16;
    short8 qf[2];
#pragma unroll
    for (int ks = 0; ks < 2; ks++)
      qf[ks] = *(const short8*)(QKb + ((size_t)b * TT + qg0 + lo) * 128 + ks * 32 + hi * 8);
    f32x4 acc[16];
#pragma unroll
    for (int nt = 0; nt < 16; nt++) acc[nt] = (f32x4){0.f, 0.f, 0.f, 0.f};
    float mrow = -3e38f, lrow = 0.f;
    int nkt = qt + 1;

    for (int kt = 0; kt < nkt; kt++) {
      int kbase = kt * KB;
      // stage K tile: pre-swizzled global source -> linear LDS (rule #21)
#pragma unroll
      for (int i = 0; i < 2; i++) {
        int c = tid + i * 256;
        int key = c >> 3;
        int dqb = (c & 7) << 4;
        const char* src = kgb + (size_t)(kbase + key) * 256 + (dqb ^ ((key & 7) << 4));
        __builtin_amdgcn_global_load_lds((const __attribute__((address_space(1))) void*)src,
            (__attribute__((address_space(3))) void*)((char*)Ks + c * 16), 16, 0, 0);
      }
      // stage V tile
#pragma unroll
      for (int i = 0; i < 8; i++) {
        int c = tid + i * 256;
        int dv = c >> 3;
        int kb2 = (c & 7) << 4;
        const char* src = vgb + (size_t)dv * (TT * 2) + kbase * 2 + (kb2 ^ ((dv & 7) << 4));
        __builtin_amdgcn_global_load_lds((const __attribute__((address_space(1))) void*)src,
            (__attribute__((address_space(3))) void*)((char*)Vs + c * 16), 16, 0, 0);
      }
      __syncthreads();

      if (kbase <= qg0 + 15) {
        // S^T = K * Q^T : 8 MFMAs
        f32x4 s[4];
#pragma unroll
        for (int mt = 0; mt < 4; mt++) s[mt] = (f32x4){0.f, 0.f, 0.f, 0.f};
#pragma unroll
        for (int ks = 0; ks < 2; ks++) {
#pragma unroll
          for (int mt = 0; mt < 4; mt++) {
            int key = mt * 16 + lo;
            short8 kf = *(const short8*)((const char*)Ks + key * 128 +
                          ((ks * 64 + hi * 16) ^ ((key & 7) << 4)));
            s[mt] = __builtin_amdgcn_mfma_f32_16x16x32_bf16(kf, qf[ks], s[mt], 0, 0, 0);
          }
        }
        // causal mask (element: key_g > q_g)
        if (kbase + KB - 1 > qg0) {
#pragma unroll
          for (int mt = 0; mt < 4; mt++)
#pragma unroll
            for (int r = 0; r < 4; r++)
              if (kbase + mt * 16 + hi * 4 + r > qg0 + lo) s[mt][r] = -3e38f;
        }
        // online softmax for q = lo (replicated over hi after shfl reduce)
        float mx = -3e38f;
#pragma unroll
        for (int mt = 0; mt < 4; mt++)
#pragma unroll
          for (int r = 0; r < 4; r++) mx = fmaxf(mx, s[mt][r]);
        mx = fmaxf(mx, __shfl_xor(mx, 16));
        mx = fmaxf(mx, __shfl_xor(mx, 32));
        float mnew = fmaxf(mrow, mx);
        float fac = exp2f((mrow - mnew) * C_EXP);
        mrow = mnew;
        float lsum = 0.f;
        char* pw = (char*)Ps[w];
#pragma unroll
        for (int mt = 0; mt < 4; mt++) {
          float p0 = exp2f((s[mt][0] - mnew) * C_EXP);
          float p1 = exp2f((s[mt][1] - mnew) * C_EXP);
          float p2 = exp2f((s[mt][2] - mnew) * C_EXP);
          float p3 = exp2f((s[mt][3] - mnew) * C_EXP);
          lsum += (p0 + p1) + (p2 + p3);
          uint2 pk;
          pk.x = (uint32_t)f2bf(p0) | ((uint32_t)f2bf(p1) << 16);
          pk.y = (uint32_t)f2bf(p2) | ((uint32_t)f2bf(p3) << 16);
          *(uint2*)(pw + lo * 128 + ((mt * 32 + hi * 8) ^ ((lo & 7) << 4))) = pk;
        }
        lsum += __shfl_xor(lsum, 16);
        lsum += __shfl_xor(lsum, 32);
        lrow = lrow * fac + lsum;
        // rescale accumulator if running max grew
        if (__any(fac < 1.f)) {
#pragma unroll
          for (int r = 0; r < 4; r++) {
            float fr = __shfl(fac, hi * 4 + r);
#pragma unroll
            for (int nt = 0; nt < 16; nt++) acc[nt][r] *= fr;
          }
        }
        // cross-lane P visibility within the wave
        asm volatile("s_waitcnt lgkmcnt(0)" ::: "memory");
        // PV: O += P * V  : 32 MFMAs
#pragma unroll
        for (int ks = 0; ks < 2; ks++) {
          short8 pf = *(const short8*)(pw + lo * 128 + ((ks * 64 + hi * 16) ^ ((lo & 7) << 4)));
#pragma unroll
          for (int nt = 0; nt < 16; nt++) {
            int dv = nt * 16 + lo;
            short8 vf = *(const short8*)((const char*)Vs + dv * 128 +
                          ((ks * 64 + hi * 16) ^ ((dv & 7) << 4)));
            acc[nt] = __builtin_amdgcn_mfma_f32_16x16x32_bf16(pf, vf, acc[nt], 0, 0, 0);
          }
        }
      }
      __syncthreads();
    }
    // epilogue: normalize + store fp32
    float invl = 1.f / lrow;
#pragma unroll
    for (int r = 0; r < 4; r++) {
      float il = __shfl(invl, hi * 4 + r);
      int qrow = qg0 + hi * 4 + r;
      float* op = Out + ((size_t)b * TT + qrow) * DM + (size_t)slice * DVS;
#pragma unroll
      for (int nt = 0; nt < 16; nt++) op[nt * 16 + lo] = acc[nt][r] * il;
    }
  }
}

extern "C" void kernel_launch(void* const* d_in, const int* in_sizes, int n_in,
                              void* d_out, int out_size, void* d_ws, size_t ws_size,
                              hipStream_t stream) {
  const float* X  = (const float*)d_in[0];
  const float* Wq = (const float*)d_in[1];
  const float* Wk = (const float*)d_in[2];
  const float* Wv = (const float*)d_in[3];
  float* Out = (float*)d_out;

  unsigned short* Xb   = (unsigned short*)d_ws;                  // 16384x1024
  unsigned short* QKb  = Xb   + (size_t)MTOT * DM;               // 16384x128
  unsigned short* Vt   = QKb  + (size_t)MTOT * 128;              // 4x1024x4096
  unsigned short* WqkT = Vt   + (size_t)NB * DM * TT;            // 128x1024
  unsigned short* WvT  = WqkT + (size_t)128 * DM;                // 1024x1024

  k_cvt_x<<<MTOT * DM / 1024, 256, 0, stream>>>(X, Xb);
  k_pack_wqk<<<dim3(DM / 256, 128), 256, 0, stream>>>(Wq, Wk, WqkT);
  k_pack_wv<<<dim3(DM / 256, DM), 256, 0, stream>>>(Wv, WvT);
  k_gemm<false><<<dim3(MTOT / 128, 1), 256, 0, stream>>>(Xb, WqkT, QKb, MTOT, 128, DM);
  k_gemm<true ><<<dim3(MTOT / 128, DM / 128), 256, 0, stream>>>(Xb, WvT, Vt, MTOT, DM, DM);
  k_flash<<<512, 256, 0, stream>>>(QKb, Vt, Out);
}